// Round 7
// baseline (53.623 us; speedup 1.0000x reference)
//
#include <hip/hip_runtime.h>
#include <hip/hip_bf16.h>

// LinearCombiner: MLP has NO activation -> affine: out = M@x + c,
// M = W3@W2@W1 (8x3072), c = (W3@W2)@b1 + W3@b2 + b3, and
// x[t,u] = [min;max;user] separable -> out[t,u,o] = P[t,o]+Q[u,o]+c[o].
//
// 3 kernels, 2 gaps (round-6: every partial+reduce stage costs a ~4us gap):
//  K1 (96 blk): M2 = W3@W2 DIRECT (full-K per block, 32-col stripes; whole W3
//               staged in LDS, K split across threads, in-block LDS reduce).
//               Writes M2 in the padded-LDS-image layout + cw3b2 = W3@b2.
//  K2 (96 blk): stage M2 (straight copy), M-chunk = M2@W1 in regs, then
//               PROJECT in-block: text blocks -> Ppart[64][256][8],
//               user blocks -> Qpart[32][128][8]. Block 0: c = M2@b1+cw3b2+b3.
//               M itself is never materialized.
//  K3 (256 blk): out[t,u,:] = sum_cb Ppart + sum_ub Qpart + c.
//
// LDS A-layout: As[PADI(k,o)] = A[o][k], PADI = k*8 + o + (k/96)*4.
// The +4 pad per 96 rows breaks bank aliasing of the 32 kq-groups
// (96 = 0 mod 32); per-iter A-read = 2 aligned ds_read_b128, conflict-free.

#define HIDN 3072
#define NF4 768            // HIDN/4
#define DIM 1024
#define NOUT 8
#define CPB 32             // cols per block
#define NBLK 96            // HIDN/CPB
#define KQ 32              // k-groups (threads >> 3)
#define KPT 96             // k per thread
#define BATCH 24
#define NBAT 4             // KPT/BATCH
#define ASZ 24704          // 3072*8 + 32*4
#define AL4 193            // f4 stride per kq (772/4)
#define TDIM 256
#define UDIM 128

#define PADI(k, o) ((k) * 8 + (o) + ((k) / 96) * 4)

__device__ __forceinline__ float4 f4z() { return make_float4(0.f, 0.f, 0.f, 0.f); }
__device__ __forceinline__ float4 f4add(float4 a, float4 b) {
    return make_float4(a.x + b.x, a.y + b.y, a.z + b.z, a.w + b.w);
}
__device__ __forceinline__ float4 f4fma(float s, float4 v, float4 a) {
    return make_float4(fmaf(s, v.x, a.x), fmaf(s, v.y, a.y),
                       fmaf(s, v.z, a.z), fmaf(s, v.w, a.w));
}
__device__ __forceinline__ float4 f4min(float4 a, float4 b) {
    return make_float4(fminf(a.x, b.x), fminf(a.y, b.y),
                       fminf(a.z, b.z), fminf(a.w, b.w));
}
__device__ __forceinline__ float4 f4max(float4 a, float4 b) {
    return make_float4(fmaxf(a.x, b.x), fmaxf(a.y, b.y),
                       fmaxf(a.z, b.z), fmaxf(a.w, b.w));
}
__device__ __forceinline__ float dot4(float4 a, float4 b) {
    return a.x * b.x + a.y * b.y + a.z * b.z + a.w * b.w;
}

// Main-loop body shared by K1/K2: acc[8] f4 over this thread's K-range.
__device__ __forceinline__ void gemm_core(const float* __restrict__ B,
                                          const float* As, int blk,
                                          int kq, int c4, float4 acc[NOUT]) {
    const float4* As4 = (const float4*)As;
    const float4* Bp = (const float4*)B + (size_t)(kq * KPT) * NF4
                       + blk * (CPB / 4) + c4;
#pragma unroll
    for (int o = 0; o < NOUT; ++o) acc[o] = f4z();
    for (int bt = 0; bt < NBAT; ++bt) {
        float4 bv[BATCH];
#pragma unroll
        for (int j = 0; j < BATCH; ++j)
            bv[j] = Bp[(size_t)(bt * BATCH + j) * NF4];
#pragma unroll
        for (int j = 0; j < BATCH; ++j) {
            const int kk = bt * BATCH + j;
            float4 a0 = As4[kq * AL4 + kk * 2];
            float4 a1 = As4[kq * AL4 + kk * 2 + 1];
            acc[0] = f4fma(a0.x, bv[j], acc[0]);
            acc[1] = f4fma(a0.y, bv[j], acc[1]);
            acc[2] = f4fma(a0.z, bv[j], acc[2]);
            acc[3] = f4fma(a0.w, bv[j], acc[3]);
            acc[4] = f4fma(a1.x, bv[j], acc[4]);
            acc[5] = f4fma(a1.y, bv[j], acc[5]);
            acc[6] = f4fma(a1.z, bv[j], acc[6]);
            acc[7] = f4fma(a1.w, bv[j], acc[7]);
        }
    }
}

// c-style dot: cdot[o] = sum_k As[o,k]*bvec[k], 32 lanes per o, lane k5==0 holds it
__device__ __forceinline__ float bias_dot(const float* As,
                                          const float* __restrict__ bvec,
                                          int tid) {
    const int o = tid >> 5, k5 = tid & 31;
    float acc = 0.f;
    for (int j = 0; j < KPT; ++j) {
        const int k = k5 + 32 * j;
        acc += As[PADI(k, o)] * bvec[k];
    }
#pragma unroll
    for (int off = 16; off; off >>= 1) acc += __shfl_down(acc, off, 32);
    return acc;   // valid on k5==0
}

// K1: M2 = W3 @ W2, direct, written in pad layout. Block 0 also cw3b2 = W3@b2.
__global__ __launch_bounds__(256) void k1_gemm(
    const float* __restrict__ W3, const float* __restrict__ W2,
    const float* __restrict__ b2, float* __restrict__ M2pad,
    float* __restrict__ cw3b2) {
    __shared__ __align__(16) float As[ASZ];
    const int tid = threadIdx.x, blk = blockIdx.x;
    const int kq = tid >> 3, c4 = tid & 7;

    // stage W3 (8x3072 row-major) into pad layout
    const float4* W34 = (const float4*)W3;
    for (int i = tid; i < (NOUT * HIDN) / 4; i += 256) {
        float4 v = W34[i];
        const int o = i / NF4, k = (i % NF4) * 4;   // 4 consecutive k, same o
        const int base = PADI(k, o);                // k..k+3 share k/96 (96%4==0)
        As[base] = v.x; As[base + 8] = v.y; As[base + 16] = v.z; As[base + 24] = v.w;
    }
    __syncthreads();

    if (blk == 0) {
        float cc = bias_dot(As, b2, tid);
        if ((tid & 31) == 0) cw3b2[tid >> 5] = cc;
    }

    float4 acc[NOUT];
    gemm_core(W2, As, blk, kq, c4, acc);

    __syncthreads();                       // As dead -> alias reduce buffer
    float4* red = (float4*)As;             // stride 33 f4 per (o*8+c4)
#pragma unroll
    for (int o = 0; o < NOUT; ++o) red[(o * 8 + c4) * 33 + kq] = acc[o];
    __syncthreads();
    if (tid < 64) {                        // tid = o*8 + cc
        float4 m = f4z();
#pragma unroll
        for (int q = 0; q < KQ; ++q) m = f4add(m, red[tid * 33 + q]);
        const int o = tid >> 3, cc = tid & 7;
        float mv[4] = {m.x, m.y, m.z, m.w};
#pragma unroll
        for (int ii = 0; ii < 4; ++ii) {
            const int k = blk * CPB + cc * 4 + ii;
            M2pad[PADI(k, o)] = mv[ii];
        }
    }
}

// K2: M-chunk = M2@W1 in regs, project to Ppart/Qpart. Block 0: c.
__global__ __launch_bounds__(256) void k2_gemm_proj(
    const float* __restrict__ M2pad, const float* __restrict__ W1,
    const float* __restrict__ ta, const float* __restrict__ tb,
    const float* __restrict__ user, const float* __restrict__ b1,
    const float* __restrict__ cw3b2, const float* __restrict__ b3,
    float* __restrict__ Ppart, float* __restrict__ Qpart,
    float* __restrict__ cvec) {
    __shared__ __align__(16) float As[ASZ];
    const int tid = threadIdx.x, blk = blockIdx.x;
    const int kq = tid >> 3, c4 = tid & 7;

    // stage M2 (already pad layout): straight f4 copy
    const float4* S4 = (const float4*)M2pad;
    float4* D4 = (float4*)As;
    for (int i = tid; i < ASZ / 4; i += 256) D4[i] = S4[i];
    __syncthreads();

    if (blk == 0) {
        float cc = bias_dot(As, b1, tid);    // M2 @ b1
        if ((tid & 31) == 0) {
            const int o = tid >> 5;
            cvec[o] = cc + cw3b2[o] + b3[o];
        }
    }

    float4 acc[NOUT];
    gemm_core(W1, As, blk, kq, c4, acc);

    __syncthreads();
    float4* red = (float4*)As;
#pragma unroll
    for (int o = 0; o < NOUT; ++o) red[(o * 8 + c4) * 33 + kq] = acc[o];
    __syncthreads();
    if (tid < 64) {                         // Mq chunk -> red[2120 + o*8 + cc]
        float4 m = f4z();
#pragma unroll
        for (int q = 0; q < KQ; ++q) m = f4add(m, red[tid * 33 + q]);
        red[2120 + tid] = m;
    }
    __syncthreads();

    if (blk < 64) {
        // text: blk<32 -> cols [0,1024) vs min ; 32..63 -> [1024,2048) vs max
        const int t = tid;
        const int dbase4 = (blk < 32 ? blk : blk - 32) * 8;
        const float4* ta4 = (const float4*)ta;
        const float4* tb4 = (const float4*)tb;
        float4 x8[8];
#pragma unroll
        for (int j = 0; j < 8; ++j) {
            float4 a = ta4[t * (DIM / 4) + dbase4 + j];
            float4 b = tb4[t * (DIM / 4) + dbase4 + j];
            x8[j] = (blk < 32) ? f4min(a, b) : f4max(a, b);
        }
        float p[NOUT];
#pragma unroll
        for (int o = 0; o < NOUT; ++o) {
            float s = 0.f;
#pragma unroll
            for (int j = 0; j < 8; ++j) s += dot4(red[2120 + o * 8 + j], x8[j]);
            p[o] = s;
        }
        float4* Pp4 = (float4*)Ppart;
        Pp4[(blk * TDIM + t) * 2]     = make_float4(p[0], p[1], p[2], p[3]);
        Pp4[(blk * TDIM + t) * 2 + 1] = make_float4(p[4], p[5], p[6], p[7]);
    } else {
        // user: cols [2048,3072), d_user = (blk-64)*32 + local
        const int ub = blk - 64;             // [0,32)
        const int u = tid >> 1, half = tid & 1;
        const float4* u4 = (const float4*)user;
        float4 x8[8];
#pragma unroll
        for (int j = 0; j < 8; ++j) x8[j] = u4[u * (DIM / 4) + ub * 8 + j];
        float q[4];
#pragma unroll
        for (int oo = 0; oo < 4; ++oo) {
            const int o = half * 4 + oo;
            float s = 0.f;
#pragma unroll
            for (int j = 0; j < 8; ++j) s += dot4(red[2120 + o * 8 + j], x8[j]);
            q[oo] = s;
        }
        ((float4*)Qpart)[(ub * UDIM + u) * 2 + half] =
            make_float4(q[0], q[1], q[2], q[3]);
    }
}

// K3: out[t,u,:] = sum_cb Ppart[cb][t] + sum_ub Qpart[ub][u] + c
__global__ __launch_bounds__(256) void k3_out(
    const float* __restrict__ Ppart, const float* __restrict__ Qpart,
    const float* __restrict__ cvec, float4* __restrict__ out) {
    __shared__ float4 l4[128];
    const int t = blockIdx.x, tid = threadIdx.x;
    const int u = tid >> 1, half = tid & 1;

    const float4* Pp4 = (const float4*)Ppart;
    if (tid < 128) l4[tid] = Pp4[((tid >> 1) * TDIM + t) * 2 + (tid & 1)];
    __syncthreads();
    if (tid < 64) l4[tid] = f4add(l4[tid], l4[tid + 64]); __syncthreads();
    if (tid < 32) l4[tid] = f4add(l4[tid], l4[tid + 32]); __syncthreads();
    if (tid < 16) l4[tid] = f4add(l4[tid], l4[tid + 16]); __syncthreads();
    if (tid < 8)  l4[tid] = f4add(l4[tid], l4[tid + 8]);  __syncthreads();
    if (tid < 4)  l4[tid] = f4add(l4[tid], l4[tid + 4]);  __syncthreads();
    if (tid < 2)  l4[tid] = f4add(l4[tid], l4[tid + 2]);  __syncthreads();

    const float4* Qp4 = (const float4*)Qpart;
    float4 q = f4z();
#pragma unroll 8
    for (int ub = 0; ub < 32; ++ub) q = f4add(q, Qp4[ub * 256 + tid]);

    float4 cv = ((const float4*)cvec)[half];
    float4 pv = l4[half];
    out[t * 256 + tid] = f4add(f4add(pv, q), cv);
}

extern "C" void kernel_launch(void* const* d_in, const int* in_sizes, int n_in,
                              void* d_out, int out_size, void* d_ws, size_t ws_size,
                              hipStream_t stream) {
    const float* text_a = (const float*)d_in[0];
    const float* text_b = (const float*)d_in[1];
    const float* user   = (const float*)d_in[2];
    const float* W1 = (const float*)d_in[3];
    const float* b1 = (const float*)d_in[4];
    const float* W2 = (const float*)d_in[5];
    const float* b2 = (const float*)d_in[6];
    const float* W3 = (const float*)d_in[7];
    const float* b3 = (const float*)d_in[8];

    float* ws = (float*)d_ws;
    float* M2pad = ws;                         // 24704 floats (pad layout)
    float* cw3b2 = M2pad + ASZ;                // 8
    float* cvec  = cw3b2 + NOUT;               // 8  (total 24720, f4-aligned)
    float* Ppart = cvec + NOUT;                // 64*256*8 = 131072
    float* Qpart = Ppart + 64 * TDIM * NOUT;   // 32*128*8 = 32768

    k1_gemm<<<NBLK, 256, 0, stream>>>(W3, W2, b2, M2pad, cw3b2);
    k2_gemm_proj<<<NBLK, 256, 0, stream>>>(M2pad, W1, text_a, text_b, user,
                                           b1, cw3b2, b3, Ppart, Qpart, cvec);
    k3_out<<<TDIM, 256, 0, stream>>>(Ppart, Qpart, cvec, (float4*)d_out);
}

// Round 8
// 46.745 us; speedup vs baseline: 1.1471x; 1.1471x over previous
//
#include <hip/hip_runtime.h>
#include <hip/hip_bf16.h>

// LinearCombiner: MLP has NO activation -> affine: out = M@x + c,
// M = W3@W2@W1 (8x3072), c = (W3@W2)@b1 + W3@b2 + b3, and
// x[t,u] = [min;max;user] separable -> out[t,u,o] = P[t,o]+Q[u,o]+c[o].
//
// Round-7 lesson: full-K blocks (96 blk, 99KB LDS) -> 96/256 CUs busy, BW
// collapses. Keep 384-block K-sliced GEMMs (round-5's best streaming), cut
// the reduce/combine stages with HW fp32 atomics instead:
//  K1 (12x32 blk): part1 = W3@W2 slices (plain, deterministic) + cp2;
//                  also zeroes M_text & Q for K2's atomics.
//  K2 (12x32 blk): self-reduce M2 slice from part1 (L2-hot), GEMM slice of
//                  M2@W1 in regs; gx<8 -> unsafeAtomicAdd into M_text;
//                  gx>=8 -> project chunk vs user in-block, atomicAdd into Q
//                  (M_user never materialized). cp1 fold.
//  K3 (256 blk):   P[t] from M_text, Q direct, c from cp1/cp2/b3, write row.
// fp atomic reorder noise ~1e-6 << 1.78e-2 threshold.

#define HIDN 3072
#define DIM 1024
#define NOUT 8
#define NS 32            // k-slices
#define KPS 96           // rows per slice
#define WK 24            // rows per wave (KPS/4)
#define GX 12            // column groups of 256 cols
#define TDIM 256
#define UDIM 128

__device__ __forceinline__ float4 f4z() { return make_float4(0.f, 0.f, 0.f, 0.f); }
__device__ __forceinline__ float4 add4(float4 a, float4 b) {
    return make_float4(a.x + b.x, a.y + b.y, a.z + b.z, a.w + b.w);
}
__device__ __forceinline__ float dot4(float4 a, float4 b) {
    return a.x * b.x + a.y * b.y + a.z * b.z + a.w * b.w;
}

// fold cp[s][o] = sum_kk As[o][kk] * bvec[s*KPS+kk]  (32 lanes per o)
__device__ __forceinline__ void bias_slice_fold(const float* As,
                                                const float* __restrict__ bvec,
                                                float* __restrict__ cp,
                                                int s, int tid) {
    const int o = tid >> 5, k5 = tid & 31;
    float acc = 0.f;
#pragma unroll
    for (int j = 0; j < KPS / 32; ++j)
        acc += As[o * KPS + k5 + 32 * j] * bvec[s * KPS + k5 + 32 * j];
#pragma unroll
    for (int off = 16; off; off >>= 1) acc += __shfl_down(acc, off, 32);
    if (k5 == 0) cp[s * NOUT + o] = acc;
}

// shared GEMM inner: acc[8] f4 over this wave's 24 rows, 24 hoisted loads
__device__ __forceinline__ void gemm_core(const float* __restrict__ B,
                                          const float* As, int s, int gx,
                                          int lane, int w, float4 acc[NOUT]) {
    const int h = gx * 256 + lane * 4;
    const int k0 = s * KPS + w * WK;
    const float4* Bp = (const float4*)(B + (size_t)k0 * HIDN) + (h >> 2);
    float4 bv[WK];
#pragma unroll
    for (int kk = 0; kk < WK; ++kk) bv[kk] = Bp[(size_t)kk * (HIDN / 4)];
#pragma unroll
    for (int o = 0; o < NOUT; ++o) acc[o] = f4z();
#pragma unroll
    for (int kk = 0; kk < WK; ++kk) {
#pragma unroll
        for (int o = 0; o < NOUT; ++o) {
            float a = As[o * KPS + w * WK + kk];
            acc[o].x += a * bv[kk].x; acc[o].y += a * bv[kk].y;
            acc[o].z += a * bv[kk].z; acc[o].w += a * bv[kk].w;
        }
    }
}

// K1: part1[s][o][h] = W3@W2 slice ; cp2 ; zero Mt & Q
__global__ __launch_bounds__(256) void k1_gemm(
    const float* __restrict__ W3, const float* __restrict__ W2,
    const float* __restrict__ b2, float* __restrict__ part1,
    float* __restrict__ cp2, float* __restrict__ Mt, float* __restrict__ Q) {
    const int s = blockIdx.y, gx = blockIdx.x;
    const int tid = threadIdx.x;
    const int lane = tid & 63, w = tid >> 6;

    // zero atomic targets for K2 (completes before K2 launches)
    const int bid = s * GX + gx;
    if (bid < 256) {
        if (tid < 64) Mt[bid * 64 + tid] = 0.f;          // 16384 floats
    } else if (bid < 272) {
        if (tid < 64) Q[(bid - 256) * 64 + tid] = 0.f;   // 1024 floats
    }

    __shared__ float As[NOUT * KPS];          // 3 KB
    __shared__ float4 red[4 * NOUT * 64];     // 32 KB

    for (int i = tid; i < NOUT * KPS; i += 256)
        As[i] = W3[(i / KPS) * HIDN + s * KPS + (i % KPS)];
    __syncthreads();
    if (gx == 0) bias_slice_fold(As, b2, cp2, s, tid);

    float4 acc[NOUT];
    gemm_core(W2, As, s, gx, lane, w, acc);

#pragma unroll
    for (int o = 0; o < NOUT; ++o) red[(w * NOUT + o) * 64 + lane] = acc[o];
    __syncthreads();
    const int h = gx * 256 + lane * 4;
#pragma unroll
    for (int j = 0; j < 2; ++j) {
        const int o = w * 2 + j;
        float4 r = add4(add4(red[(0 * NOUT + o) * 64 + lane],
                             red[(1 * NOUT + o) * 64 + lane]),
                        add4(red[(2 * NOUT + o) * 64 + lane],
                             red[(3 * NOUT + o) * 64 + lane]));
        *(float4*)(part1 + ((size_t)s * NOUT + o) * HIDN + h) = r;
    }
}

// K2: self-reduce M2 slice; GEMM slice of M2@W1; text cols -> atomic Mt,
// user cols -> in-block projection -> atomic Q. cp1 fold on gx==0.
__global__ __launch_bounds__(256) void k2_gemm(
    const float* __restrict__ part1, const float* __restrict__ W1,
    const float* __restrict__ user, const float* __restrict__ b1,
    float* __restrict__ cp1, float* __restrict__ Mt, float* __restrict__ Q) {
    const int s = blockIdx.y, gx = blockIdx.x;
    const int tid = threadIdx.x;
    const int lane = tid & 63, w = tid >> 6;

    __shared__ float As[NOUT * KPS];          // 3 KB
    __shared__ float4 red[4 * NOUT * 64];     // 32 KB
    __shared__ float4 Mu4[NOUT * 64];         // 8 KB  (user-chunk rows)

    // As[o][kk] = sum_sp part1[sp][o][s*KPS+kk]  (L2/L3-hot, f4)
    for (int j4 = tid; j4 < NOUT * KPS / 4; j4 += 256) {
        const int o = j4 / (KPS / 4), kk4 = j4 % (KPS / 4);
        const float4* pp = (const float4*)(part1 + (size_t)o * HIDN
                                           + s * KPS) + kk4;
        float4 a = f4z();
#pragma unroll 8
        for (int sp = 0; sp < NS; ++sp)
            a = add4(a, pp[(size_t)sp * (NOUT * HIDN / 4)]);
        ((float4*)As)[j4] = a;
    }
    __syncthreads();
    if (gx == 0) bias_slice_fold(As, b1, cp1, s, tid);

    float4 acc[NOUT];
    gemm_core(W1, As, s, gx, lane, w, acc);

#pragma unroll
    for (int o = 0; o < NOUT; ++o) red[(w * NOUT + o) * 64 + lane] = acc[o];
    __syncthreads();

    if (gx < 8) {
        // text columns: accumulate into Mt[o][gx*256 + lane*4 ..]
        const int h = gx * 256 + lane * 4;
#pragma unroll
        for (int j = 0; j < 2; ++j) {
            const int o = w * 2 + j;
            float4 r = add4(add4(red[(0 * NOUT + o) * 64 + lane],
                                 red[(1 * NOUT + o) * 64 + lane]),
                            add4(red[(2 * NOUT + o) * 64 + lane],
                                 red[(3 * NOUT + o) * 64 + lane]));
            float* dst = Mt + o * 2048 + h;
            unsafeAtomicAdd(dst + 0, r.x);
            unsafeAtomicAdd(dst + 1, r.y);
            unsafeAtomicAdd(dst + 2, r.z);
            unsafeAtomicAdd(dst + 3, r.w);
        }
    } else {
        // user columns: chunk -> LDS, project vs user, atomic into Q
#pragma unroll
        for (int j = 0; j < 2; ++j) {
            const int o = w * 2 + j;
            Mu4[o * 64 + lane] = add4(add4(red[(0 * NOUT + o) * 64 + lane],
                                           red[(1 * NOUT + o) * 64 + lane]),
                                      add4(red[(2 * NOUT + o) * 64 + lane],
                                           red[(3 * NOUT + o) * 64 + lane]));
        }
        __syncthreads();
        const int u = tid >> 1, o0 = (tid & 1) * 4;
        const float4* uv = (const float4*)user + (size_t)u * (DIM / 4)
                           + (gx - 8) * 64;
        float q[4] = {0.f, 0.f, 0.f, 0.f};
        for (int j = 0; j < 64; ++j) {
            float4 x = uv[j];
#pragma unroll
            for (int oo = 0; oo < 4; ++oo)
                q[oo] += dot4(Mu4[(o0 + oo) * 64 + j], x);
        }
#pragma unroll
        for (int oo = 0; oo < 4; ++oo)
            unsafeAtomicAdd(Q + u * NOUT + o0 + oo, q[oo]);
    }
}

// K3: out[t,u,:] = P[t] + Q[u] + c   (256 t-blocks)
__global__ __launch_bounds__(256) void k3_out(
    const float* __restrict__ ta, const float* __restrict__ tb,
    const float* __restrict__ Mt, const float* __restrict__ Q,
    const float* __restrict__ cp1, const float* __restrict__ cp2,
    const float* __restrict__ b3, float4* __restrict__ out) {
    const int t = blockIdx.x, tid = threadIdx.x;
    const int lane = tid & 63, w = tid >> 6;

    const float4* Mt4 = (const float4*)Mt;
    float4 a = ((const float4*)ta)[(size_t)t * (DIM / 4) + tid];
    float4 b = ((const float4*)tb)[(size_t)t * (DIM / 4) + tid];
    float4 mn = make_float4(fminf(a.x, b.x), fminf(a.y, b.y),
                            fminf(a.z, b.z), fminf(a.w, b.w));
    float4 mx = make_float4(fmaxf(a.x, b.x), fmaxf(a.y, b.y),
                            fmaxf(a.z, b.z), fmaxf(a.w, b.w));
    float acc[NOUT];
#pragma unroll
    for (int o = 0; o < NOUT; ++o) {
        float4 ml = Mt4[o * 512 + tid];          // cols 0..1023 (min half)
        float4 mh = Mt4[o * 512 + 256 + tid];    // cols 1024..2047 (max half)
        acc[o] = dot4(ml, mn) + dot4(mh, mx);
    }
#pragma unroll
    for (int o = 0; o < NOUT; ++o) {
#pragma unroll
        for (int off = 32; off > 0; off >>= 1)
            acc[o] += __shfl_down(acc[o], off, 64);
    }
    __shared__ float red[4][NOUT];
    __shared__ float c8[NOUT];
    if (lane == 0) {
#pragma unroll
        for (int o = 0; o < NOUT; ++o) red[w][o] = acc[o];
    }
    if (tid < NOUT) {
        float cc = b3[tid];
#pragma unroll 8
        for (int s = 0; s < NS; ++s)
            cc += cp1[s * NOUT + tid] + cp2[s * NOUT + tid];
        c8[tid] = cc;
    }
    __syncthreads();

    const int u = tid >> 1, half = tid & 1, o0 = half * 4;
    float4 q = ((const float4*)Q)[u * 2 + half];
    float4 pv = make_float4(
        red[0][o0 + 0] + red[1][o0 + 0] + red[2][o0 + 0] + red[3][o0 + 0],
        red[0][o0 + 1] + red[1][o0 + 1] + red[2][o0 + 1] + red[3][o0 + 1],
        red[0][o0 + 2] + red[1][o0 + 2] + red[2][o0 + 2] + red[3][o0 + 2],
        red[0][o0 + 3] + red[1][o0 + 3] + red[2][o0 + 3] + red[3][o0 + 3]);
    float4 cv = make_float4(c8[o0], c8[o0 + 1], c8[o0 + 2], c8[o0 + 3]);
    out[(size_t)t * 256 + tid] = add4(add4(pv, q), cv);
}

extern "C" void kernel_launch(void* const* d_in, const int* in_sizes, int n_in,
                              void* d_out, int out_size, void* d_ws, size_t ws_size,
                              hipStream_t stream) {
    const float* text_a = (const float*)d_in[0];
    const float* text_b = (const float*)d_in[1];
    const float* user   = (const float*)d_in[2];
    const float* W1 = (const float*)d_in[3];
    const float* b1 = (const float*)d_in[4];
    const float* W2 = (const float*)d_in[5];
    const float* b2 = (const float*)d_in[6];
    const float* W3 = (const float*)d_in[7];
    const float* b3 = (const float*)d_in[8];

    float* ws = (float*)d_ws;
    float* part1 = ws;                                  // 786432 floats
    float* Mt    = part1 + (size_t)NS * NOUT * HIDN;    // 16384 (8x2048)
    float* Q     = Mt + NOUT * 2048;                    // 1024 (128x8)
    float* cp1   = Q + UDIM * NOUT;                     // 256
    float* cp2   = cp1 + NS * NOUT;                     // 256

    // K1: part1 = W3 @ W2 ; cp2 ; zero Mt/Q
    k1_gemm<<<dim3(GX, NS), 256, 0, stream>>>(W3, W2, b2, part1, cp2, Mt, Q);
    // K2: M2 slice self-reduce ; slice of M2@W1 -> atomic Mt / project->Q ; cp1
    k2_gemm<<<dim3(GX, NS), 256, 0, stream>>>(part1, W1, user, b1, cp1, Mt, Q);
    // K3: out
    k3_out<<<TDIM, 256, 0, stream>>>(text_a, text_b, Mt, Q, cp1, cp2, b3,
                                     (float4*)d_out);
}

// Round 9
// 33.794 us; speedup vs baseline: 1.5867x; 1.3832x over previous
//
#include <hip/hip_runtime.h>
#include <hip/hip_bf16.h>

// LinearCombiner: MLP has NO activation -> affine: out = M@x + c,
// M = W3@W2@W1 (8x3072), c = (W3@W2)@b1 + W3@b2 + b3, and
// x[t,u] = [min;max;user] separable -> out[t,u,o] = P[t,o]+Q[u,o]+c[o].
//
// Round-8 lesson: fp atomics into Mt/Q cost ~13us (32-way per-address
// contention) — plain writes + one extra kernel is cheaper. Structure:
//  K1 (12x32): part1 = W3@W2 k-slice partials + cp2          [R5, proven]
//  K2 (12x32): self-reduce M2 slice from part1 (L2-hot), part2 = M2@W1
//              k-slice partials + cp1                        [R5, proven]
//  K3 (97):    b<64  : Mt (8x2048 text cols) = reduce part2
//              b<96  : 32-col M_user chunk reduce (LDS) + project vs user
//                      -> Qpart[32][128][8]  (M_user never materialized)
//              b==96 : c = sum(cp1+cp2)+b3
//  K4 (256):   P[t] from Mt + Q = sum_ub Qpart + c -> out row  (1MB write)

#define HIDN 3072
#define DIM 1024
#define NOUT 8
#define NS 32            // k-slices
#define KPS 96           // rows per slice
#define WK 24            // rows per wave (KPS/4)
#define GX 12            // column groups of 256 cols
#define TDIM 256
#define UDIM 128
#define PF4 6144         // NOUT*HIDN/4 (f4 stride between slice partials)

__device__ __forceinline__ float4 f4z() { return make_float4(0.f, 0.f, 0.f, 0.f); }
__device__ __forceinline__ float4 add4(float4 a, float4 b) {
    return make_float4(a.x + b.x, a.y + b.y, a.z + b.z, a.w + b.w);
}
__device__ __forceinline__ float dot4(float4 a, float4 b) {
    return a.x * b.x + a.y * b.y + a.z * b.z + a.w * b.w;
}

// fold cp[s][o] = sum_kk As[o][kk] * bvec[s*KPS+kk]  (32 lanes per o)
__device__ __forceinline__ void bias_slice_fold(const float* As,
                                                const float* __restrict__ bvec,
                                                float* __restrict__ cp,
                                                int s, int tid) {
    const int o = tid >> 5, k5 = tid & 31;
    float acc = 0.f;
#pragma unroll
    for (int j = 0; j < KPS / 32; ++j)
        acc += As[o * KPS + k5 + 32 * j] * bvec[s * KPS + k5 + 32 * j];
#pragma unroll
    for (int off = 16; off; off >>= 1) acc += __shfl_down(acc, off, 32);
    if (k5 == 0) cp[s * NOUT + o] = acc;
}

// mode 0: A_rows (8,HIDN) read directly. mode 1: A slice self-reduced from
// part_in. part_out[s][o][h] = sum_{k in slice s} A[o,k] * B[k,h]
__global__ __launch_bounds__(256) void gemm_partial(
    const float* __restrict__ A_rows, const float* __restrict__ part_in,
    const float* __restrict__ B, float* __restrict__ part_out,
    const float* __restrict__ bvec, float* __restrict__ cp, int mode) {
    const int s = blockIdx.y, gx = blockIdx.x;
    const int tid = threadIdx.x;
    const int lane = tid & 63, w = tid >> 6;

    __shared__ float As[NOUT * KPS];          // 3 KB
    __shared__ float4 red[4 * NOUT * 64];     // 32 KB

    if (mode == 0) {
        for (int i = tid; i < NOUT * KPS; i += 256)
            As[i] = A_rows[(i / KPS) * HIDN + s * KPS + (i % KPS)];
    } else {
        for (int j4 = tid; j4 < NOUT * KPS / 4; j4 += 256) {
            const int o = j4 / (KPS / 4), kk4 = j4 % (KPS / 4);
            const float4* pp = (const float4*)(part_in + (size_t)o * HIDN
                                               + s * KPS) + kk4;
            float4 a = f4z();
#pragma unroll 8
            for (int sp = 0; sp < NS; ++sp)
                a = add4(a, pp[(size_t)sp * PF4]);
            ((float4*)As)[j4] = a;
        }
    }
    __syncthreads();
    if (gx == 0) bias_slice_fold(As, bvec, cp, s, tid);

    const int h = gx * 256 + lane * 4;
    const int k0 = s * KPS + w * WK;
    const float4* Bp = (const float4*)(B + (size_t)k0 * HIDN) + (h >> 2);

    float4 bv[WK];                             // 24 hoisted loads, ~24KB/wave
#pragma unroll
    for (int kk = 0; kk < WK; ++kk) bv[kk] = Bp[(size_t)kk * (HIDN / 4)];

    float4 acc[NOUT];
#pragma unroll
    for (int o = 0; o < NOUT; ++o) acc[o] = f4z();
#pragma unroll
    for (int kk = 0; kk < WK; ++kk) {
#pragma unroll
        for (int o = 0; o < NOUT; ++o) {
            float a = As[o * KPS + w * WK + kk];
            acc[o].x += a * bv[kk].x; acc[o].y += a * bv[kk].y;
            acc[o].z += a * bv[kk].z; acc[o].w += a * bv[kk].w;
        }
    }

#pragma unroll
    for (int o = 0; o < NOUT; ++o) red[(w * NOUT + o) * 64 + lane] = acc[o];
    __syncthreads();
#pragma unroll
    for (int j = 0; j < 2; ++j) {
        const int o = w * 2 + j;
        float4 r = add4(add4(red[(0 * NOUT + o) * 64 + lane],
                             red[(1 * NOUT + o) * 64 + lane]),
                        add4(red[(2 * NOUT + o) * 64 + lane],
                             red[(3 * NOUT + o) * 64 + lane]));
        *(float4*)(part_out + ((size_t)s * NOUT + o) * HIDN + h) = r;
    }
}

// K3: b<64: Mt reduce ; b in [64,96): M_user chunk reduce + user projection ;
//     b==96: c.
__global__ __launch_bounds__(256) void k3_mid(
    const float* __restrict__ part2, const float* __restrict__ user,
    const float* __restrict__ cp1, const float* __restrict__ cp2,
    const float* __restrict__ b3, float* __restrict__ Mt,
    float* __restrict__ Qpart, float* __restrict__ cvec) {
    const int b = blockIdx.x, tid = threadIdx.x;
    const float4* p4 = (const float4*)part2;

    if (b < 64) {
        // Mt: 4096 f4 total; block owns 64 f4; 4 waves split 32 slices.
        const int lane = tid & 63, w = tid >> 6;
        const int i4 = b * 64 + lane;            // [0,4096): o = i4>>9, h4 = i4&511
        const int o = i4 >> 9, h4 = i4 & 511;
        float4 acc = f4z();
#pragma unroll
        for (int j = 0; j < 8; ++j)
            acc = add4(acc, p4[(size_t)(w * 8 + j) * PF4 + o * 768 + h4]);
        __shared__ float4 red2[4 * 64];
        red2[w * 64 + lane] = acc;
        __syncthreads();
        if (w == 0) {
            float4 r = add4(add4(red2[lane], red2[64 + lane]),
                            add4(red2[128 + lane], red2[192 + lane]));
            ((float4*)Mt)[i4] = r;
        }
        return;
    }

    if (b < 96) {
        // user chunk ub: cols4 [512+ub*8, 512+ub*8+8) -> dims [ub*32, ub*32+32)
        const int ub = b - 64;
        __shared__ float4 mup[4 * 64];
        __shared__ float4 Mu4[NOUT * 8];         // Mu[8][32] as f4
        const int tgt = tid & 63, grp = tid >> 6;
        const int o = tgt >> 3, j4 = tgt & 7;
        float4 a = f4z();
#pragma unroll
        for (int j = 0; j < 8; ++j)
            a = add4(a, p4[(size_t)(grp * 8 + j) * PF4 + o * 768 + 512 + ub * 8 + j4]);
        mup[grp * 64 + tgt] = a;
        __syncthreads();
        if (tid < 64)
            Mu4[tid] = add4(add4(mup[tid], mup[64 + tid]),
                            add4(mup[128 + tid], mup[192 + tid]));
        __syncthreads();

        const int u = tid >> 1, o0 = (tid & 1) * 4;
        const float4* uv = (const float4*)user + (size_t)u * (DIM / 4) + ub * 8;
        float4 x8[8];
#pragma unroll
        for (int j = 0; j < 8; ++j) x8[j] = uv[j];
        float q[4];
#pragma unroll
        for (int oo = 0; oo < 4; ++oo) {
            float s = 0.f;
#pragma unroll
            for (int j = 0; j < 8; ++j) s += dot4(Mu4[(o0 + oo) * 8 + j], x8[j]);
            q[oo] = s;
        }
        ((float4*)Qpart)[((size_t)ub * UDIM + (tid >> 1)) * 2 + (tid & 1)] =
            make_float4(q[0], q[1], q[2], q[3]);
        return;
    }

    if (tid < NOUT) {                            // b == 96: c
        float cc = b3[tid];
#pragma unroll 8
        for (int s = 0; s < NS; ++s)
            cc += cp1[s * NOUT + tid] + cp2[s * NOUT + tid];
        cvec[tid] = cc;
    }
}

// K4: out[t,u,:] = P[t] + sum_ub Qpart[ub][u] + c   (256 t-blocks)
__global__ __launch_bounds__(256) void k4_out(
    const float* __restrict__ ta, const float* __restrict__ tb,
    const float* __restrict__ Mt, const float* __restrict__ Qpart,
    const float* __restrict__ cvec, float4* __restrict__ out) {
    const int t = blockIdx.x, tid = threadIdx.x;
    const int lane = tid & 63, w = tid >> 6;

    const float4* Mt4 = (const float4*)Mt;
    float4 a = ((const float4*)ta)[(size_t)t * (DIM / 4) + tid];
    float4 b = ((const float4*)tb)[(size_t)t * (DIM / 4) + tid];
    float4 mn = make_float4(fminf(a.x, b.x), fminf(a.y, b.y),
                            fminf(a.z, b.z), fminf(a.w, b.w));
    float4 mx = make_float4(fmaxf(a.x, b.x), fmaxf(a.y, b.y),
                            fmaxf(a.z, b.z), fmaxf(a.w, b.w));
    float acc[NOUT];
#pragma unroll
    for (int o = 0; o < NOUT; ++o) {
        float4 ml = Mt4[o * 512 + tid];          // dims 0..1023 (min half)
        float4 mh = Mt4[o * 512 + 256 + tid];    // dims 1024..2047 (max half)
        acc[o] = dot4(ml, mn) + dot4(mh, mx);
    }
#pragma unroll
    for (int o = 0; o < NOUT; ++o) {
#pragma unroll
        for (int off = 32; off > 0; off >>= 1)
            acc[o] += __shfl_down(acc[o], off, 64);
    }
    __shared__ float red[4][NOUT];
    if (lane == 0) {
#pragma unroll
        for (int o = 0; o < NOUT; ++o) red[w][o] = acc[o];
    }
    __syncthreads();

    const int u = tid >> 1, half = tid & 1, o0 = half * 4;
    const float4* Qp4 = (const float4*)Qpart;
    float4 q = f4z();
#pragma unroll 8
    for (int ub = 0; ub < 32; ++ub)
        q = add4(q, Qp4[((size_t)ub * UDIM + u) * 2 + half]);

    float4 cv = ((const float4*)cvec)[half];
    float4 pv = make_float4(
        red[0][o0 + 0] + red[1][o0 + 0] + red[2][o0 + 0] + red[3][o0 + 0],
        red[0][o0 + 1] + red[1][o0 + 1] + red[2][o0 + 1] + red[3][o0 + 1],
        red[0][o0 + 2] + red[1][o0 + 2] + red[2][o0 + 2] + red[3][o0 + 2],
        red[0][o0 + 3] + red[1][o0 + 3] + red[2][o0 + 3] + red[3][o0 + 3]);
    out[(size_t)t * 256 + tid] = add4(add4(pv, q), cv);
}

extern "C" void kernel_launch(void* const* d_in, const int* in_sizes, int n_in,
                              void* d_out, int out_size, void* d_ws, size_t ws_size,
                              hipStream_t stream) {
    const float* text_a = (const float*)d_in[0];
    const float* text_b = (const float*)d_in[1];
    const float* user   = (const float*)d_in[2];
    const float* W1 = (const float*)d_in[3];
    const float* b1 = (const float*)d_in[4];
    const float* W2 = (const float*)d_in[5];
    const float* b2 = (const float*)d_in[6];
    const float* W3 = (const float*)d_in[7];
    const float* b3 = (const float*)d_in[8];

    float* ws = (float*)d_ws;
    float* part1 = ws;                                  // 786432 floats
    float* part2 = part1 + (size_t)NS * NOUT * HIDN;    // 786432
    float* Mt    = part2 + (size_t)NS * NOUT * HIDN;    // 16384 (8x2048)
    float* Qpart = Mt + NOUT * 2048;                    // 32768 (32x128x8)
    float* cp1   = Qpart + 32 * UDIM * NOUT;            // 256
    float* cp2   = cp1 + NS * NOUT;                     // 256
    float* cvec  = cp2 + NS * NOUT;                     // 8

    // K1: part1 = W3 @ W2 ; cp2
    gemm_partial<<<dim3(GX, NS), 256, 0, stream>>>(W3, nullptr, W2, part1,
                                                   b2, cp2, 0);
    // K2: As = M2 slice (self-reduce from part1) ; part2 = M2 @ W1 ; cp1
    gemm_partial<<<dim3(GX, NS), 256, 0, stream>>>(nullptr, part1, W1, part2,
                                                   b1, cp1, 1);
    // K3: Mt reduce + Qpart projection + c
    k3_mid<<<97, 256, 0, stream>>>(part2, user, cp1, cp2, b3, Mt, Qpart, cvec);
    // K4: out
    k4_out<<<TDIM, 256, 0, stream>>>(text_a, text_b, Mt, Qpart, cvec,
                                     (float4*)d_out);
}

// Round 10
// 33.009 us; speedup vs baseline: 1.6245x; 1.0238x over previous
//
#include <hip/hip_runtime.h>
#include <hip/hip_bf16.h>

// LinearCombiner: MLP has NO activation -> affine: out = M@x + c,
// M = W3@W2@W1 (8x3072), c = (W3@W2)@b1 + W3@b2 + b3, and
// x[t,u] = [min;max;user] separable -> out[t,u,o] = P[t,o]+Q[u,o]+c[o].
//
// Structure (4 launches):
//  K1 (24x32): part1 = W3@W2 k-slice partials + cp2
//  K2 (24x32): self-reduce M2 slice from part1 (L2-hot), part2 = M2@W1 + cp1
//  K3 (97):    Mt reduce (text cols) / M_user chunk reduce + user proj / c
//  K4 (256):   P[t] from Mt + Q = sum Qpart + c -> out row (1MB)
//
// Round-10 change: GEMM grid 384 -> 768 blocks (3/CU EXACTLY). 384 blocks
// left 128 CUs with 2x the bytes (196KB) while 128 idled at half-time ->
// ~25% BW loss. 768 blocks x 128 cols balances per-CU bytes at 147KB.

#define HIDN 3072
#define DIM 1024
#define NOUT 8
#define NS 32            // k-slices
#define KPS 96           // rows per slice
#define RPT 12           // rows per thread (KPS / 8 row-groups)
#define GX 24            // column groups of 128 cols
#define CPB 128          // cols per block (32 f4)
#define TDIM 256
#define UDIM 128
#define PF4 6144         // NOUT*HIDN/4 (f4 stride between slice partials)

__device__ __forceinline__ float4 f4z() { return make_float4(0.f, 0.f, 0.f, 0.f); }
__device__ __forceinline__ float4 add4(float4 a, float4 b) {
    return make_float4(a.x + b.x, a.y + b.y, a.z + b.z, a.w + b.w);
}
__device__ __forceinline__ float dot4(float4 a, float4 b) {
    return a.x * b.x + a.y * b.y + a.z * b.z + a.w * b.w;
}

// fold cp[s][o] = sum_kk As[o][kk] * bvec[s*KPS+kk]  (32 lanes per o)
__device__ __forceinline__ void bias_slice_fold(const float* As,
                                                const float* __restrict__ bvec,
                                                float* __restrict__ cp,
                                                int s, int tid) {
    const int o = tid >> 5, k5 = tid & 31;
    float acc = 0.f;
#pragma unroll
    for (int j = 0; j < KPS / 32; ++j)
        acc += As[o * KPS + k5 + 32 * j] * bvec[s * KPS + k5 + 32 * j];
#pragma unroll
    for (int off = 16; off; off >>= 1) acc += __shfl_down(acc, off, 32);
    if (k5 == 0) cp[s * NOUT + o] = acc;
}

// mode 0: A_rows (8,HIDN) read directly. mode 1: A slice self-reduced from
// part_in. part_out[s][o][h] = sum_{k in slice s} A[o,k] * B[k,h]
// Block: 96 rows x 128 cols. Thread: rq = tid>>5 (12 rows), c4 = tid&31.
__global__ __launch_bounds__(256) void gemm_partial(
    const float* __restrict__ A_rows, const float* __restrict__ part_in,
    const float* __restrict__ B, float* __restrict__ part_out,
    const float* __restrict__ bvec, float* __restrict__ cp, int mode) {
    const int s = blockIdx.y, gx = blockIdx.x;
    const int tid = threadIdx.x;
    const int rq = tid >> 5, c4 = tid & 31;

    __shared__ float As[NOUT * KPS];          // 3 KB
    __shared__ float4 red[8 * NOUT * 32];     // 32 KB: [rq][o][c4]

    if (mode == 0) {
        for (int i = tid; i < NOUT * KPS; i += 256)
            As[i] = A_rows[(i / KPS) * HIDN + s * KPS + (i % KPS)];
    } else {
        // As[o][kk] = sum_sp part_in[sp][o][s*KPS+kk]  (L2/L3-hot, f4)
        if (tid < NOUT * KPS / 4) {
            const int j4 = tid;
            const int o = j4 / (KPS / 4), kk4 = j4 % (KPS / 4);
            const float4* pp = (const float4*)(part_in + (size_t)o * HIDN
                                               + s * KPS) + kk4;
            float4 a = f4z();
#pragma unroll 8
            for (int sp = 0; sp < NS; ++sp)
                a = add4(a, pp[(size_t)sp * PF4]);
            ((float4*)As)[j4] = a;
        }
    }
    __syncthreads();
    if (gx == 0) bias_slice_fold(As, bvec, cp, s, tid);

    const int k0 = s * KPS + rq * RPT;
    const float4* Bp = (const float4*)(B + (size_t)k0 * HIDN) + gx * 32 + c4;

    float4 bv[RPT];                            // 12 hoisted loads, 12KB/wave
#pragma unroll
    for (int kk = 0; kk < RPT; ++kk) bv[kk] = Bp[(size_t)kk * (HIDN / 4)];

    float4 acc[NOUT];
#pragma unroll
    for (int o = 0; o < NOUT; ++o) acc[o] = f4z();
#pragma unroll
    for (int kk = 0; kk < RPT; ++kk) {
#pragma unroll
        for (int o = 0; o < NOUT; ++o) {
            float a = As[o * KPS + rq * RPT + kk];
            acc[o].x += a * bv[kk].x; acc[o].y += a * bv[kk].y;
            acc[o].z += a * bv[kk].z; acc[o].w += a * bv[kk].w;
        }
    }

    // cross-row-group reduce: red[rq][o][c4], then thread (o,c4) sums 8 rq
#pragma unroll
    for (int o = 0; o < NOUT; ++o) red[rq * 256 + o * 32 + c4] = acc[o];
    __syncthreads();
    {
        const int o = tid >> 5, cc = tid & 31;   // 256 threads = 8 o x 32 c4
        float4 r = f4z();
#pragma unroll
        for (int q = 0; q < 8; ++q) r = add4(r, red[q * 256 + o * 32 + cc]);
        *(float4*)(part_out + ((size_t)s * NOUT + o) * HIDN + gx * CPB + cc * 4) = r;
    }
}

// K3: b<64: Mt reduce ; b in [64,96): M_user chunk reduce + user projection ;
//     b==96: c.
__global__ __launch_bounds__(256) void k3_mid(
    const float* __restrict__ part2, const float* __restrict__ user,
    const float* __restrict__ cp1, const float* __restrict__ cp2,
    const float* __restrict__ b3, float* __restrict__ Mt,
    float* __restrict__ Qpart, float* __restrict__ cvec) {
    const int b = blockIdx.x, tid = threadIdx.x;
    const float4* p4 = (const float4*)part2;

    if (b < 64) {
        // Mt: 4096 f4 total; block owns 64 f4; 4 waves split 32 slices.
        const int lane = tid & 63, w = tid >> 6;
        const int i4 = b * 64 + lane;            // [0,4096): o = i4>>9, h4 = i4&511
        const int o = i4 >> 9, h4 = i4 & 511;
        float4 acc = f4z();
#pragma unroll
        for (int j = 0; j < 8; ++j)
            acc = add4(acc, p4[(size_t)(w * 8 + j) * PF4 + o * 768 + h4]);
        __shared__ float4 red2[4 * 64];
        red2[w * 64 + lane] = acc;
        __syncthreads();
        if (w == 0) {
            float4 r = add4(add4(red2[lane], red2[64 + lane]),
                            add4(red2[128 + lane], red2[192 + lane]));
            ((float4*)Mt)[i4] = r;
        }
        return;
    }

    if (b < 96) {
        // user chunk ub: cols4 [512+ub*8, +8) -> user dims [ub*32, +32)
        const int ub = b - 64;
        __shared__ float4 mup[4 * 64];
        __shared__ float4 Mu4[NOUT * 8];         // Mu[8][32] as f4
        const int tgt = tid & 63, grp = tid >> 6;
        const int o = tgt >> 3, j4 = tgt & 7;
        float4 a = f4z();
#pragma unroll
        for (int j = 0; j < 8; ++j)
            a = add4(a, p4[(size_t)(grp * 8 + j) * PF4 + o * 768 + 512 + ub * 8 + j4]);
        mup[grp * 64 + tgt] = a;
        __syncthreads();
        if (tid < 64)
            Mu4[tid] = add4(add4(mup[tid], mup[64 + tid]),
                            add4(mup[128 + tid], mup[192 + tid]));
        __syncthreads();

        const int u = tid >> 1, o0 = (tid & 1) * 4;
        const float4* uv = (const float4*)user + (size_t)u * (DIM / 4) + ub * 8;
        float4 x8[8];
#pragma unroll
        for (int j = 0; j < 8; ++j) x8[j] = uv[j];
        float q[4];
#pragma unroll
        for (int oo = 0; oo < 4; ++oo) {
            float s = 0.f;
#pragma unroll
            for (int j = 0; j < 8; ++j) s += dot4(Mu4[(o0 + oo) * 8 + j], x8[j]);
            q[oo] = s;
        }
        ((float4*)Qpart)[((size_t)ub * UDIM + u) * 2 + (tid & 1)] =
            make_float4(q[0], q[1], q[2], q[3]);
        return;
    }

    if (tid < NOUT) {                            // b == 96: c
        float cc = b3[tid];
#pragma unroll 8
        for (int s = 0; s < NS; ++s)
            cc += cp1[s * NOUT + tid] + cp2[s * NOUT + tid];
        cvec[tid] = cc;
    }
}

// K4: out[t,u,:] = P[t] + sum_ub Qpart[ub][u] + c   (256 t-blocks)
__global__ __launch_bounds__(256) void k4_out(
    const float* __restrict__ ta, const float* __restrict__ tb,
    const float* __restrict__ Mt, const float* __restrict__ Qpart,
    const float* __restrict__ cvec, float4* __restrict__ out) {
    const int t = blockIdx.x, tid = threadIdx.x;
    const int lane = tid & 63, w = tid >> 6;

    const float4* Mt4 = (const float4*)Mt;
    float4 a = ((const float4*)ta)[(size_t)t * (DIM / 4) + tid];
    float4 b = ((const float4*)tb)[(size_t)t * (DIM / 4) + tid];
    float4 mn = make_float4(fminf(a.x, b.x), fminf(a.y, b.y),
                            fminf(a.z, b.z), fminf(a.w, b.w));
    float4 mx = make_float4(fmaxf(a.x, b.x), fmaxf(a.y, b.y),
                            fmaxf(a.z, b.z), fmaxf(a.w, b.w));
    float acc[NOUT];
#pragma unroll
    for (int o = 0; o < NOUT; ++o) {
        float4 ml = Mt4[o * 512 + tid];          // dims 0..1023 (min half)
        float4 mh = Mt4[o * 512 + 256 + tid];    // dims 1024..2047 (max half)
        acc[o] = dot4(ml, mn) + dot4(mh, mx);
    }
#pragma unroll
    for (int o = 0; o < NOUT; ++o) {
#pragma unroll
        for (int off = 32; off > 0; off >>= 1)
            acc[o] += __shfl_down(acc[o], off, 64);
    }
    __shared__ float red[4][NOUT];
    if (lane == 0) {
#pragma unroll
        for (int o = 0; o < NOUT; ++o) red[w][o] = acc[o];
    }
    __syncthreads();

    const int u = tid >> 1, half = tid & 1, o0 = half * 4;
    const float4* Qp4 = (const float4*)Qpart;
    float4 q = f4z();
#pragma unroll 8
    for (int ub = 0; ub < 32; ++ub)
        q = add4(q, Qp4[((size_t)ub * UDIM + u) * 2 + half]);

    float4 cv = ((const float4*)cvec)[half];
    float4 pv = make_float4(
        red[0][o0 + 0] + red[1][o0 + 0] + red[2][o0 + 0] + red[3][o0 + 0],
        red[0][o0 + 1] + red[1][o0 + 1] + red[2][o0 + 1] + red[3][o0 + 1],
        red[0][o0 + 2] + red[1][o0 + 2] + red[2][o0 + 2] + red[3][o0 + 2],
        red[0][o0 + 3] + red[1][o0 + 3] + red[2][o0 + 3] + red[3][o0 + 3]);
    out[(size_t)t * 256 + tid] = add4(add4(pv, q), cv);
}

extern "C" void kernel_launch(void* const* d_in, const int* in_sizes, int n_in,
                              void* d_out, int out_size, void* d_ws, size_t ws_size,
                              hipStream_t stream) {
    const float* text_a = (const float*)d_in[0];
    const float* text_b = (const float*)d_in[1];
    const float* user   = (const float*)d_in[2];
    const float* W1 = (const float*)d_in[3];
    const float* b1 = (const float*)d_in[4];
    const float* W2 = (const float*)d_in[5];
    const float* b2 = (const float*)d_in[6];
    const float* W3 = (const float*)d_in[7];
    const float* b3 = (const float*)d_in[8];

    float* ws = (float*)d_ws;
    float* part1 = ws;                                  // 786432 floats
    float* part2 = part1 + (size_t)NS * NOUT * HIDN;    // 786432
    float* Mt    = part2 + (size_t)NS * NOUT * HIDN;    // 16384 (8x2048)
    float* Qpart = Mt + NOUT * 2048;                    // 32768 (32x128x8)
    float* cp1   = Qpart + 32 * UDIM * NOUT;            // 256
    float* cp2   = cp1 + NS * NOUT;                     // 256
    float* cvec  = cp2 + NS * NOUT;                     // 8

    // K1: part1 = W3 @ W2 ; cp2
    gemm_partial<<<dim3(GX, NS), 256, 0, stream>>>(W3, nullptr, W2, part1,
                                                   b2, cp2, 0);
    // K2: As = M2 slice (self-reduce from part1) ; part2 = M2 @ W1 ; cp1
    gemm_partial<<<dim3(GX, NS), 256, 0, stream>>>(nullptr, part1, W1, part2,
                                                   b1, cp1, 1);
    // K3: Mt reduce + Qpart projection + c
    k3_mid<<<97, 256, 0, stream>>>(part2, user, cp1, cp2, b3, Mt, Qpart, cvec);
    // K4: out
    k4_out<<<TDIM, 256, 0, stream>>>(text_a, text_b, Mt, Qpart, cvec,
                                     (float4*)d_out);
}